// Round 4
// baseline (74.168 us; speedup 1.0000x reference)
//
#include <hip/hip_runtime.h>

#define NN 262144
#define DD 32
#define HH 31
#define KK 21
#define CAP 16384                 // per-bucket capacity; expected ~12483 rows/bucket
#define ENTRIES (KK * CAP)

// ---------------- Kernel 1: bucketize rows by t ----------------
__global__ __launch_bounds__(256) void bucketize_kernel(
    const float* __restrict__ x,
    int* __restrict__ entries,    // [KK][CAP]
    int* __restrict__ cursors,    // [KK], pre-zeroed
    float* __restrict__ out)
{
    __shared__ int lcnt[KK];
    __shared__ int lbase[KK];
    __shared__ int lrank[KK];

    const int tid = threadIdx.x;
    if (tid < KK) { lcnt[tid] = 0; lrank[tid] = 0; }
    __syncthreads();

    const int n = blockIdx.x * 256 + tid;
    const float t = x[n * DD];

    // Exact same comparisons as reference: t > edges[k] && t <= edges[k+1]
    const float edges[KK + 1] = {
        0.0f, 0.1f, 0.2f, 0.3f, 0.4f, 0.5f, 0.6f, 0.7f, 0.8f, 0.9f, 1.0f,
        1.1f, 1.2f, 1.3f, 1.4f, 1.5f, 1.6f, 1.7f, 1.8f, 1.9f, 2.0f, 1000.0f
    };
    int k = -1;
    #pragma unroll
    for (int j = 0; j < KK; ++j)
        if (t > edges[j] && t <= edges[j + 1]) k = j;

    if (k >= 0) atomicAdd(&lcnt[k], 1);
    __syncthreads();
    if (tid < KK) lbase[tid] = atomicAdd(&cursors[tid], lcnt[tid]);
    __syncthreads();
    if (k >= 0) {
        const int r = atomicAdd(&lrank[k], 1);
        const int pos = lbase[k] + r;
        if (pos < CAP) entries[k * CAP + pos] = n;
    } else {
        out[n] = 0.0f;   // rows outside every bucket
    }
}

// ---------------- Kernel 2: per-bucket MLP, block-uniform k ----------------
// CAP/256 = 64 blocks per bucket -> k = blockIdx.x>>6 is block-uniform.
// e-outer / d-inner so the live set is feats[31] + 2 accumulators (~40 VGPR):
// fits the compiler's 48-reg choice with NO scratch spill.
__global__ __launch_bounds__(256) void mlp_sorted_kernel(
    const float* __restrict__ x,
    const float* __restrict__ a,
    const float* __restrict__ b,
    const float* __restrict__ W1,
    const float* __restrict__ b1,
    const float* __restrict__ W2,
    const float* __restrict__ b2,
    const int* __restrict__ entries,
    const int* __restrict__ cursors,
    float* __restrict__ out)
{
    const int k = __builtin_amdgcn_readfirstlane((int)blockIdx.x >> 6);
    const int local = (((int)blockIdx.x & 63) << 8) + (int)threadIdx.x;

    int cnt = cursors[k];
    if (cnt > CAP) cnt = CAP;
    if (local >= cnt) return;

    const int n = entries[k * CAP + local];

    // Phase 1: gather the row (8 independent 16B loads), fold into feats.
    float feats[HH + 1];   // feats[0..30] used; one pad slot for pair-unroll
    {
        float row[DD];
        const float4* xp = reinterpret_cast<const float4*>(x) + n * (DD / 4);
        #pragma unroll
        for (int i4 = 0; i4 < DD / 4; ++i4) {
            float4 v = xp[i4];
            row[4 * i4 + 0] = v.x;
            row[4 * i4 + 1] = v.y;
            row[4 * i4 + 2] = v.z;
            row[4 * i4 + 3] = v.w;
        }
        #pragma unroll
        for (int j = 0; j < HH; ++j) feats[j] = fmaf(row[j + 1], a[j], b[j]);
        feats[HH] = 0.0f;
    }

    // Phase 2: e-outer, d-inner. Two independent chains (e, e+1) per step.
    const float* __restrict__ w1k = W1 + k * (HH * HH);
    const float* __restrict__ b1k = b1 + k * HH;
    const float* __restrict__ w2k = W2 + k * HH;

    float acc = b2[k];
    #pragma unroll
    for (int e = 0; e < HH; e += 2) {
        float h0 = b1k[e];
        float h1 = (e + 1 < HH) ? b1k[e + 1] : 0.0f;
        const float* __restrict__ c0 = w1k + e;        // column e, stride HH
        #pragma unroll
        for (int d = 0; d < HH; ++d) {
            const float fd = feats[d];
            h0 = fmaf(fd, c0[d * HH], h0);
            if (e + 1 < HH) h1 = fmaf(fd, c0[d * HH + 1], h1);
        }
        const float r0 = (h0 >= 0.0f) ? h0 : 0.1f * h0;
        acc = fmaf(r0, w2k[e], acc);
        if (e + 1 < HH) {
            const float r1 = (h1 >= 0.0f) ? h1 : 0.1f * h1;
            acc = fmaf(r1, w2k[e + 1], acc);
        }
    }
    out[n] = acc;
}

extern "C" void kernel_launch(void* const* d_in, const int* in_sizes, int n_in,
                              void* d_out, int out_size, void* d_ws, size_t ws_size,
                              hipStream_t stream) {
    const float* x  = (const float*)d_in[0];
    const float* a  = (const float*)d_in[1];
    const float* b  = (const float*)d_in[2];
    const float* W1 = (const float*)d_in[3];
    const float* b1 = (const float*)d_in[4];
    const float* W2 = (const float*)d_in[5];
    const float* b2 = (const float*)d_in[6];
    float* out = (float*)d_out;

    int* entries = (int*)d_ws;
    int* cursors = entries + ENTRIES;

    hipMemsetAsync(cursors, 0, KK * sizeof(int), stream);

    hipLaunchKernelGGL(bucketize_kernel, dim3(NN / 256), dim3(256), 0, stream,
                       x, entries, cursors, out);

    hipLaunchKernelGGL(mlp_sorted_kernel, dim3(KK * (CAP / 256)), dim3(256), 0, stream,
                       x, a, b, W1, b1, W2, b2, entries, cursors, out);
}

// Round 5
// 46.863 us; speedup vs baseline: 1.5827x; 1.5827x over previous
//
#include <hip/hip_runtime.h>

#define NN 262144
#define DD 32
#define HH 31
#define KK 21
#define CAP 16384                 // per-bucket capacity; expected ~12483 rows/bucket
#define ENTRIES (KK * CAP)
#define W1T_KSTRIDE (HH * 32)     // [k][e][d], d padded 31->32 (16B aligned rows)

// ---------------- Kernel 0: transpose W1 to [k][e][d] + zero cursors --------
__global__ __launch_bounds__(256) void prep_kernel(
    const float* __restrict__ W1,   // [K][d][e]
    float* __restrict__ W1T,        // [K][e][32]
    int* __restrict__ cursors)
{
    const int idx = blockIdx.x * 256 + threadIdx.x;
    if (blockIdx.x == 0 && threadIdx.x < KK) cursors[threadIdx.x] = 0;
    if (idx >= KK * HH * HH) return;
    const int k = idx / (HH * HH);
    const int r = idx % (HH * HH);
    const int d = r / HH;
    const int e = r % HH;
    W1T[k * W1T_KSTRIDE + e * 32 + d] = W1[idx];
}

// ---------------- Kernel 1: bucketize rows by t ----------------
__global__ __launch_bounds__(256) void bucketize_kernel(
    const float* __restrict__ x,
    int* __restrict__ entries,    // [KK][CAP]
    int* __restrict__ cursors,    // [KK], zeroed by prep_kernel
    float* __restrict__ out)
{
    __shared__ int lcnt[KK];
    __shared__ int lbase[KK];
    __shared__ int lrank[KK];

    const int tid = threadIdx.x;
    if (tid < KK) { lcnt[tid] = 0; lrank[tid] = 0; }
    __syncthreads();

    const int n = blockIdx.x * 256 + tid;
    const float t = x[n * DD];

    // Exact same comparisons as reference: t > edges[k] && t <= edges[k+1]
    const float edges[KK + 1] = {
        0.0f, 0.1f, 0.2f, 0.3f, 0.4f, 0.5f, 0.6f, 0.7f, 0.8f, 0.9f, 1.0f,
        1.1f, 1.2f, 1.3f, 1.4f, 1.5f, 1.6f, 1.7f, 1.8f, 1.9f, 2.0f, 1000.0f
    };
    int k = -1;
    #pragma unroll
    for (int j = 0; j < KK; ++j)
        if (t > edges[j] && t <= edges[j + 1]) k = j;

    if (k >= 0) atomicAdd(&lcnt[k], 1);
    __syncthreads();
    if (tid < KK) lbase[tid] = atomicAdd(&cursors[tid], lcnt[tid]);
    __syncthreads();
    if (k >= 0) {
        const int r = atomicAdd(&lrank[k], 1);
        const int pos = lbase[k] + r;
        if (pos < CAP) entries[k * CAP + pos] = n;
    } else {
        out[n] = 0.0f;   // rows outside every bucket
    }
}

// ---------------- Kernel 2: per-bucket MLP, block-uniform k ----------------
// CAP/256 = 64 blocks per bucket -> k = blockIdx.x>>6 is block-uniform.
// Weights come from W1T[k][e][d]: 31 CONTIGUOUS floats per e -> the scalar
// pipe batches them as s_load_dwordx16/x8 (2 waits per e, pipelined across
// the 62 FMAs of the e-pair). Live VGPRs ~= feats[31] + 2 chains: no spill.
__global__ __launch_bounds__(256) void mlp_sorted_kernel(
    const float* __restrict__ x,
    const float* __restrict__ a,
    const float* __restrict__ b,
    const float* __restrict__ W1T,
    const float* __restrict__ b1,
    const float* __restrict__ W2,
    const float* __restrict__ b2,
    const int* __restrict__ entries,
    const int* __restrict__ cursors,
    float* __restrict__ out)
{
    const int k = __builtin_amdgcn_readfirstlane((int)blockIdx.x >> 6);
    const int local = (((int)blockIdx.x & 63) << 8) + (int)threadIdx.x;

    int cnt = cursors[k];
    if (cnt > CAP) cnt = CAP;
    if (local >= cnt) return;

    const int n = entries[k * CAP + local];

    // Phase 1: gather the row (8 independent 16B loads), fold into feats.
    float feats[HH];
    {
        float row[DD];
        const float4* xp = reinterpret_cast<const float4*>(x) + n * (DD / 4);
        #pragma unroll
        for (int i4 = 0; i4 < DD / 4; ++i4) {
            float4 v = xp[i4];
            row[4 * i4 + 0] = v.x;
            row[4 * i4 + 1] = v.y;
            row[4 * i4 + 2] = v.z;
            row[4 * i4 + 3] = v.w;
        }
        #pragma unroll
        for (int j = 0; j < HH; ++j) feats[j] = fmaf(row[j + 1], a[j], b[j]);
    }

    // Phase 2: e-pairs, d-inner over contiguous transposed weight rows.
    const float* __restrict__ w1t = W1T + k * W1T_KSTRIDE;
    const float* __restrict__ b1k = b1 + k * HH;
    const float* __restrict__ w2k = W2 + k * HH;

    float acc = b2[k];
    #pragma unroll
    for (int e = 0; e < HH - 1; e += 2) {
        const float* __restrict__ r0 = w1t + e * 32;
        const float* __restrict__ r1 = r0 + 32;
        float h0 = b1k[e];
        float h1 = b1k[e + 1];
        #pragma unroll
        for (int d = 0; d < HH; ++d) {
            const float fd = feats[d];
            h0 = fmaf(fd, r0[d], h0);
            h1 = fmaf(fd, r1[d], h1);
        }
        const float q0 = (h0 >= 0.0f) ? h0 : 0.1f * h0;
        const float q1 = (h1 >= 0.0f) ? h1 : 0.1f * h1;
        acc = fmaf(q0, w2k[e], acc);
        acc = fmaf(q1, w2k[e + 1], acc);
    }
    {   // tail e = 30
        const float* __restrict__ r0 = w1t + (HH - 1) * 32;
        float h0 = b1k[HH - 1];
        #pragma unroll
        for (int d = 0; d < HH; ++d) h0 = fmaf(feats[d], r0[d], h0);
        const float q0 = (h0 >= 0.0f) ? h0 : 0.1f * h0;
        acc = fmaf(q0, w2k[HH - 1], acc);
    }
    out[n] = acc;
}

extern "C" void kernel_launch(void* const* d_in, const int* in_sizes, int n_in,
                              void* d_out, int out_size, void* d_ws, size_t ws_size,
                              hipStream_t stream) {
    const float* x  = (const float*)d_in[0];
    const float* a  = (const float*)d_in[1];
    const float* b  = (const float*)d_in[2];
    const float* W1 = (const float*)d_in[3];
    const float* b1 = (const float*)d_in[4];
    const float* W2 = (const float*)d_in[5];
    const float* b2 = (const float*)d_in[6];
    float* out = (float*)d_out;

    int* entries = (int*)d_ws;                       // ENTRIES ints
    int* cursors = entries + ENTRIES;                // KK ints
    float* W1T   = (float*)(cursors + 32);           // KK*31*32 floats

    hipLaunchKernelGGL(prep_kernel, dim3((KK * HH * HH + 255) / 256), dim3(256),
                       0, stream, W1, W1T, cursors);

    hipLaunchKernelGGL(bucketize_kernel, dim3(NN / 256), dim3(256), 0, stream,
                       x, entries, cursors, out);

    hipLaunchKernelGGL(mlp_sorted_kernel, dim3(KK * (CAP / 256)), dim3(256), 0, stream,
                       x, a, b, W1T, b1, W2, b2, entries, cursors, out);
}